// Round 3
// baseline (2382.774 us; speedup 1.0000x reference)
//
#include <hip/hip_runtime.h>
#include <hip/hip_bf16.h>

#define CCH 128
#define HHH 128
#define WWW 128
#define HWX 16384           // H*W
#define NHD 4
#define HD  32
#define SCALE 0.17677669529663687f
#define LOG2E 1.4426950408889634f

typedef unsigned int  u32;
typedef unsigned short u16;
typedef short s16x8 __attribute__((ext_vector_type(8)));   // 8 bf16 (4 VGPRs)
typedef float f32x4 __attribute__((ext_vector_type(4)));   // MFMA C/D frag

__device__ __forceinline__ u16 f2bf(float f) {
  u32 u = __float_as_uint(f);
  u += 0x7fffu + ((u >> 16) & 1u);
  return (u16)(u >> 16);
}
__device__ __forceinline__ u32 pk2(float a, float b) {
  return (u32)f2bf(a) | ((u32)f2bf(b) << 16);
}
// pack two fp32 -> 2 bf16 with round-half-up (cheap: 2 adds + 1 perm)
__device__ __forceinline__ u32 pkru(float a, float b) {
  u32 ua = __float_as_uint(a) + 0x8000u;
  u32 ub = __float_as_uint(b) + 0x8000u;
  return __builtin_amdgcn_perm(ub, ua, 0x07060302);  // [ub.hi16 : ua.hi16]
}

// ---------------- weight swizzle into MFMA fragment layouts (bf16)
// wfq: B-frag layout for qkv GEMM; q rows pre-scaled by SCALE*LOG2E (attn uses exp2)
__global__ __launch_bounds__(256) void wtrans_kernel(
    const float* __restrict__ qk_w, const float* __restrict__ v_w,
    const float* __restrict__ proj_w, u16* __restrict__ wfq, u16* __restrict__ wfp) {
  int idx = blockIdx.x * 256 + threadIdx.x;          // 0..65535
  if (idx < 49152) {
    int j = idx & 7, l = (idx >> 3) & 63, kk = (idx >> 9) & 3, nt = idx >> 11;
    int k = kk * 32 + (l >> 4) * 8 + j;
    int oc = nt * 16 + (l & 15);
    float val;
    if (oc < 256) { val = qk_w[oc * 128 + k]; if (oc < 128) val *= SCALE * LOG2E; }
    else          { val = v_w[(oc - 256) * 128 + k]; }
    wfq[idx] = f2bf(val);
  } else {
    int r = idx - 49152;                             // 0..16383
    int j = r & 7, l = (r >> 3) & 63, kk = (r >> 9) & 3, mt = r >> 11;
    int oc = mt * 16 + (l & 15);
    int k = kk * 32 + (l >> 4) * 8 + j;
    wfp[r] = f2bf(proj_w[oc * 128 + k]);
  }
}

// ---------------- argmax over sims[pix][256] -> L[pix], first-index tie-break
__global__ __launch_bounds__(256) void argmax_kernel(
    const float* __restrict__ sims, int* __restrict__ L) {
  const int wave = threadIdx.x >> 6, lane = threadIdx.x & 63;
  const int pix = blockIdx.x * 4 + wave;
  const float4 s4 = *(const float4*)(sims + (size_t)pix * 256 + lane * 4);
  float bv = s4.x; int bi = lane * 4;
  if (s4.y > bv) { bv = s4.y; bi = lane * 4 + 1; }
  if (s4.z > bv) { bv = s4.z; bi = lane * 4 + 2; }
  if (s4.w > bv) { bv = s4.w; bi = lane * 4 + 3; }
  #pragma unroll
  for (int off = 32; off > 0; off >>= 1) {
    float ov = __shfl_down(bv, off);
    int   oi = __shfl_down(bi, off);
    if (ov > bv || (ov == bv && oi < bi)) { bv = ov; bi = oi; }
  }
  if (lane == 0) L[pix] = bi;
}

// ---------------- QKV GEMM (MFMA): x[b][c][hw] fp32 -> q/k/v bf16 [pix][128]
__global__ __launch_bounds__(256) void qkv_kernel(
    const float* __restrict__ x, const u16* __restrict__ wfq,
    u16* __restrict__ qb, u16* __restrict__ kb, u16* __restrict__ vb) {
  __shared__ __align__(16) u16 xs[64 * 136];         // [pix][c], pad 136 shorts
  const int t = threadIdx.x;
  const int pg0 = blockIdx.x * 64;
  const int b = blockIdx.x >> 8;
  const int hw0 = pg0 & (HWX - 1);
  const float* xb = x + (size_t)b * (CCH * HWX) + hw0;
  u32* xsw = (u32*)xs;
  #pragma unroll
  for (int it = 0; it < 16; ++it) {
    int flat = t + it * 256;                         // 0..4095 = 64 c2 x 64 pix
    int pix = flat & 63, c2 = flat >> 6;
    float f0 = xb[(size_t)(2 * c2) * HWX + pix];
    float f1 = xb[(size_t)(2 * c2 + 1) * HWX + pix];
    xsw[pix * 68 + c2] = pk2(f0, f1);
  }
  __syncthreads();

  const int w = t >> 6, lane = t & 63;
  const int l15 = lane & 15, quad = lane >> 4;

  s16x8 af[4][4];                                    // [mtile][kstep]
  #pragma unroll
  for (int m = 0; m < 4; ++m)
    #pragma unroll
    for (int kk = 0; kk < 4; ++kk)
      af[m][kk] = *(const s16x8*)(xs + (m * 16 + l15) * 136 + kk * 32 + quad * 8);

  f32x4 acc[6][4];                                   // [ntile][mtile]
  #pragma unroll
  for (int nt = 0; nt < 6; ++nt)
    #pragma unroll
    for (int m = 0; m < 4; ++m) acc[nt][m] = (f32x4){0.f, 0.f, 0.f, 0.f};

  const u16* wl = wfq + lane * 8;
  #pragma unroll
  for (int nt = 0; nt < 6; ++nt) {
    const int ntg = w * 6 + nt;
    s16x8 bf[4];
    #pragma unroll
    for (int kk = 0; kk < 4; ++kk)
      bf[kk] = *(const s16x8*)(wl + (size_t)(ntg * 4 + kk) * 512);
    #pragma unroll
    for (int m = 0; m < 4; ++m)
      #pragma unroll
      for (int kk = 0; kk < 4; ++kk)
        acc[nt][m] = __builtin_amdgcn_mfma_f32_16x16x32_bf16(af[m][kk], bf[kk], acc[nt][m], 0, 0, 0);
  }

  // epilogue: D row = pix = m*16 + quad*4 + r, col = oc = ntg*16 + l15
  #pragma unroll
  for (int nt = 0; nt < 6; ++nt) {
    const int oc = (w * 6 + nt) * 16 + l15;
    u16* base; int off;
    if (oc < 128)      { base = qb; off = oc; }
    else if (oc < 256) { base = kb; off = oc - 128; }
    else               { base = vb; off = oc - 256; }
    #pragma unroll
    for (int m = 0; m < 4; ++m) {
      const int pr = pg0 + m * 16 + quad * 4;
      #pragma unroll
      for (int r = 0; r < 4; ++r)
        base[((size_t)(pr + r) << 7) + off] = f2bf(acc[nt][m][r]);
    }
  }
}

// ---------------- attention (MFMA): block = 16x16 query tile x 1 head
// S^T = K.Q^T (M=64key chunk, N=256 query, K=32), mask+exp2, P via wave-private
// LDS round-trip, out^T = V^T.P (M=32d, N=query, K=64key).
#define VROW 520   // vT row length (u16), 1040 B: 16B-aligned, bank-stride 4
#define PROW 72    // pT row length (u16), 144 B: 16B-aligned
__global__ __launch_bounds__(256, 2) void attn_kernel(
    const u16* __restrict__ qb, const u16* __restrict__ kb, const u16* __restrict__ vb,
    const int* __restrict__ L, u16* __restrict__ aob) {
  __shared__ __align__(16) u16 vT[32 * VROW];        // V^T [d][key] 33280 B
  __shared__ __align__(16) u16 pT[256 * PROW];       // P [q_local][key64] 36864 B
  __shared__ u32 meta[512];                          // label | kc<<8 | rowmask16<<16
  const int t = threadIdx.x;
  const int bid = blockIdx.x;
  const int h = bid & 3, tj = (bid >> 2) & 7, ti = (bid >> 5) & 7, b = bid >> 8;
  const int i0 = ti * 16, j0 = tj * 16;
  const int r0 = i0 - 3, c0 = j0 - 3;                // neighborhood origin (may be <0)
  const size_t bbase = (size_t)b * HWX;

  // ---- stage V^T (transpose scatter) : 512 keys x 4 dquads
  #pragma unroll
  for (int it = 0; it < 8; ++it) {
    int flat = t + it * 256;                         // 0..2047
    int key = flat >> 2, dq = flat & 3;
    int kr = key / 22, kc = key - kr * 22;
    int pr = min(max(r0 + kr, 0), HHH - 1), pc = min(max(c0 + kc, 0), WWW - 1);
    size_t g = ((bbase + (size_t)pr * WWW + pc) << 7) + h * HD + dq * 8;
    uint4 vv = *(const uint4*)(vb + g);
    u16* cb = vT + key + (size_t)(dq * 8) * VROW;
    cb[0 * VROW] = (u16)vv.x; cb[1 * VROW] = (u16)(vv.x >> 16);
    cb[2 * VROW] = (u16)vv.y; cb[3 * VROW] = (u16)(vv.y >> 16);
    cb[4 * VROW] = (u16)vv.z; cb[5 * VROW] = (u16)(vv.z >> 16);
    cb[6 * VROW] = (u16)vv.w; cb[7 * VROW] = (u16)(vv.w >> 16);
  }
  // ---- stage meta
  #pragma unroll
  for (int it = 0; it < 2; ++it) {
    int key = t + it * 256;
    int kr = key / 22, kc = key - kr * 22;
    int pr = min(max(r0 + kr, 0), HHH - 1), pc = min(max(c0 + kc, 0), WWW - 1);
    int lab = L[bbase + (size_t)pr * WWW + pc];
    u32 rm = 0;
    #pragma unroll
    for (int nt = 0; nt < 16; ++nt) {
      int rs = min(max(i0 + nt - 3, 0), HHH - 7) - r0;
      rm |= (u32)((u32)(kr - rs) <= 6u) << nt;
    }
    meta[key] = (u32)lab | ((u32)kc << 8) | (rm << 16);
  }
  __syncthreads();

  const int w = t >> 6, lane = t & 63;
  const int l15 = lane & 15, quad = lane >> 4;
  const int qj = j0 + l15;
  const u32 cs_rel = (u32)(min(max(qj - 3, 0), WWW - 7) - c0);
  const int ntg0 = w * 4;

  u32 slab[4];
  int qrow[4];
  s16x8 qf[4];                                       // Q B-frags from global
  #pragma unroll
  for (int nt = 0; nt < 4; ++nt) {
    int qi = i0 + ntg0 + nt;
    slab[nt] = (u32)(((qi >> 3) << 4) | (qj >> 3));
    qrow[nt] = ((ntg0 + nt) * 16 + l15) * PROW;
    qf[nt] = *(const s16x8*)(qb + ((bbase + (size_t)qi * WWW + qj) << 7) + h * HD + quad * 8);
  }

  f32x4 o[2][4];
  #pragma unroll
  for (int dmt = 0; dmt < 2; ++dmt)
    #pragma unroll
    for (int nt = 0; nt < 4; ++nt) o[dmt][nt] = (f32x4){0.f, 0.f, 0.f, 0.f};
  float sa[4] = {0.f, 0.f, 0.f, 0.f}, sm[4] = {0.f, 0.f, 0.f, 0.f};

  auto loadkf = [&](s16x8* dst, int ch) {
    #pragma unroll
    for (int mt = 0; mt < 4; ++mt) {
      int key = ch * 64 + mt * 16 + l15;
      int kr = key / 22, kc = key - kr * 22;
      int pr = min(max(r0 + kr, 0), HHH - 1), pc = min(max(c0 + kc, 0), WWW - 1);
      dst[mt] = *(const s16x8*)(kb + ((bbase + (size_t)pr * WWW + pc) << 7) + h * HD + quad * 8);
    }
  };

  auto body = [&](const s16x8* kf, int ch) {
    f32x4 s_[4][4];                                  // [mt key-tile][nt query-tile]
    #pragma unroll
    for (int mt = 0; mt < 4; ++mt)
      #pragma unroll
      for (int nt = 0; nt < 4; ++nt)
        s_[mt][nt] = __builtin_amdgcn_mfma_f32_16x16x32_bf16(kf[mt], qf[nt], (f32x4){0.f,0.f,0.f,0.f}, 0, 0, 0);
    // mask + exp2 + accumulate + pack into pT
    #pragma unroll
    for (int mt = 0; mt < 4; ++mt) {
      const int keyb = ch * 64 + mt * 16 + quad * 4;
      u32 me[4];
      #pragma unroll
      for (int r = 0; r < 4; ++r) me[r] = meta[keyb + r];
      #pragma unroll
      for (int nt = 0; nt < 4; ++nt) {
        float pv[4];
        #pragma unroll
        for (int r = 0; r < 4; ++r) {
          u32 mm = me[r];
          u32 win = (u32)(((mm >> 8) & 31u) - cs_rel <= 6u) & ((mm >> (16 + ntg0 + nt)) & 1u);
          u32 mem = win & (u32)((mm & 0xFFu) == slab[nt]);
          float e = exp2f(s_[mt][nt][r]);
          sa[nt] += win ? e : 0.f;
          float p = mem ? e : 0.f;
          sm[nt] += p;
          pv[r] = p;
        }
        *(uint2*)(pT + qrow[nt] + mt * 16 + quad * 4) = make_uint2(pkru(pv[0], pv[1]), pkru(pv[2], pv[3]));
      }
    }
    // PV: out^T += V^T . P   (wave-private pT rows; in-wave DS ordering suffices)
    #pragma unroll
    for (int kk = 0; kk < 2; ++kk) {
      s16x8 pf[4];
      #pragma unroll
      for (int nt = 0; nt < 4; ++nt)
        pf[nt] = *(const s16x8*)(pT + qrow[nt] + kk * 32 + quad * 8);
      #pragma unroll
      for (int dmt = 0; dmt < 2; ++dmt) {
        s16x8 vf = *(const s16x8*)(vT + (size_t)(dmt * 16 + l15) * VROW + ch * 64 + kk * 32 + quad * 8);
        #pragma unroll
        for (int nt = 0; nt < 4; ++nt)
          o[dmt][nt] = __builtin_amdgcn_mfma_f32_16x16x32_bf16(vf, pf[nt], o[dmt][nt], 0, 0, 0);
      }
    }
  };

  s16x8 kf0[4], kf1[4];
  loadkf(kf0, 0);
  #pragma unroll
  for (int cp = 0; cp < 4; ++cp) {
    loadkf(kf1, 2 * cp + 1);
    body(kf0, 2 * cp);
    if (cp < 3) loadkf(kf0, 2 * cp + 2);
    body(kf1, 2 * cp + 1);
  }

  // epilogue: reduce sa/sm across quads, scale, store out^T -> aob[pix][128]
  #pragma unroll
  for (int nt = 0; nt < 4; ++nt) {
    float a = sa[nt], m = sm[nt];
    a += __shfl_xor(a, 16); a += __shfl_xor(a, 32);
    m += __shfl_xor(m, 16); m += __shfl_xor(m, 32);
    const float inv = 1.f / (m + 1e-8f * a);
    const size_t pix = bbase + (size_t)(i0 + ntg0 + nt) * WWW + qj;
    u16* op = aob + (pix << 7) + h * HD + quad * 4;
    #pragma unroll
    for (int dmt = 0; dmt < 2; ++dmt) {
      f32x4 oo = o[dmt][nt];
      *(uint2*)(op + dmt * 16) = make_uint2(pk2(oo[0] * inv, oo[1] * inv),
                                            pk2(oo[2] * inv, oo[3] * inv));
    }
  }
}

// ---------------- proj GEMM (MFMA): ao bf16 [pix][128] @ wfp -> out fp32 [b][oc][hw]
__global__ __launch_bounds__(256) void proj_kernel(
    const u16* __restrict__ aob, const u16* __restrict__ wfp, float* __restrict__ out) {
  __shared__ __align__(16) u16 as_[64 * 136];
  const int t = threadIdx.x;
  const int pg0 = blockIdx.x * 64;
  const int b = blockIdx.x >> 8;
  const int hw0 = pg0 & (HWX - 1);
  #pragma unroll
  for (int it = 0; it < 4; ++it) {
    int flat = t + it * 256;                         // 0..1023 = 64 pix x 16 k8
    int pix = flat >> 4, k8 = flat & 15;
    uint4 v = *(const uint4*)(aob + ((size_t)(pg0 + pix) << 7) + k8 * 8);
    *(uint4*)(as_ + pix * 136 + k8 * 8) = v;
  }
  __syncthreads();

  const int w = t >> 6, lane = t & 63;
  const int l15 = lane & 15, quad = lane >> 4;

  s16x8 aw[2][4];                                    // [mt][kstep] from wfp
  const u16* wl = wfp + lane * 8;
  #pragma unroll
  for (int mt = 0; mt < 2; ++mt)
    #pragma unroll
    for (int kk = 0; kk < 4; ++kk)
      aw[mt][kk] = *(const s16x8*)(wl + (size_t)((2 * w + mt) * 4 + kk) * 512);

  f32x4 acc[2][4];                                   // [mt][nt]
  #pragma unroll
  for (int mt = 0; mt < 2; ++mt)
    #pragma unroll
    for (int nt = 0; nt < 4; ++nt) acc[mt][nt] = (f32x4){0.f, 0.f, 0.f, 0.f};

  #pragma unroll
  for (int nt = 0; nt < 4; ++nt) {
    s16x8 bf[4];
    #pragma unroll
    for (int kk = 0; kk < 4; ++kk)
      bf[kk] = *(const s16x8*)(as_ + (nt * 16 + l15) * 136 + kk * 32 + quad * 8);
    #pragma unroll
    for (int mt = 0; mt < 2; ++mt)
      #pragma unroll
      for (int kk = 0; kk < 4; ++kk)
        acc[mt][nt] = __builtin_amdgcn_mfma_f32_16x16x32_bf16(aw[mt][kk], bf[kk], acc[mt][nt], 0, 0, 0);
  }

  float* ob = out + (size_t)b * (CCH * HWX) + hw0;
  #pragma unroll
  for (int mt = 0; mt < 2; ++mt) {
    const int oc0 = (2 * w + mt) * 16 + quad * 4;
    #pragma unroll
    for (int nt = 0; nt < 4; ++nt) {
      const int pix = nt * 16 + l15;
      #pragma unroll
      for (int r = 0; r < 4; ++r)
        ob[(size_t)(oc0 + r) * HWX + pix] = acc[mt][nt][r];
    }
  }
}

extern "C" void kernel_launch(void* const* d_in, const int* in_sizes, int n_in,
                              void* d_out, int out_size, void* d_ws, size_t ws_size,
                              hipStream_t stream) {
  const float* x      = (const float*)d_in[0];
  const float* sims   = (const float*)d_in[1];
  const float* qk_w   = (const float*)d_in[2];
  const float* v_w    = (const float*)d_in[3];
  const float* proj_w = (const float*)d_in[4];
  float* out = (float*)d_out;

  // ws: q 32MiB | k 32MiB | v 32MiB | ao 32MiB (all bf16 [pix][128]) | L | wfq | wfp
  u16* qb  = (u16*)d_ws;
  u16* kb  = qb + 16777216;
  u16* vb  = kb + 16777216;
  u16* aob = vb + 16777216;
  int* L   = (int*)(aob + 16777216);
  u16* wfq = (u16*)(L + 131072);
  u16* wfp = wfq + 49152;

  wtrans_kernel<<<256, 256, 0, stream>>>(qk_w, v_w, proj_w, wfq, wfp);
  argmax_kernel<<<32768, 256, 0, stream>>>(sims, L);
  qkv_kernel<<<2048, 256, 0, stream>>>(x, wfq, qb, kb, vb);
  attn_kernel<<<2048, 256, 0, stream>>>(qb, kb, vb, L, aob);
  proj_kernel<<<2048, 256, 0, stream>>>(aob, wfp, out);
}

// Round 4
// 409.141 us; speedup vs baseline: 5.8238x; 5.8238x over previous
//
#include <hip/hip_runtime.h>
#include <hip/hip_bf16.h>

#define CCH 128
#define HHH 128
#define WWW 128
#define HWX 16384           // H*W
#define NHD 4
#define HD  32
#define SCALE 0.17677669529663687f
#define LOG2E 1.4426950408889634f

typedef unsigned int  u32;
typedef unsigned short u16;
typedef short s16x8 __attribute__((ext_vector_type(8)));   // 8 bf16 (4 VGPRs)
typedef float f32x4 __attribute__((ext_vector_type(4)));   // MFMA C/D frag

__device__ __forceinline__ u16 f2bf(float f) {
  u32 u = __float_as_uint(f);
  u += 0x7fffu + ((u >> 16) & 1u);
  return (u16)(u >> 16);
}
__device__ __forceinline__ u32 pk2(float a, float b) {
  return (u32)f2bf(a) | ((u32)f2bf(b) << 16);
}
// pack two fp32 -> 2 bf16 round-half-up (cheap: 2 adds + 1 perm); p >= 0 always
__device__ __forceinline__ u32 pkru(float a, float b) {
  u32 ua = __float_as_uint(a) + 0x8000u;
  u32 ub = __float_as_uint(b) + 0x8000u;
  return __builtin_amdgcn_perm(ub, ua, 0x07060302);  // [ub.hi16 : ua.hi16]
}

// ---------------- weight swizzle into MFMA fragment layouts (bf16)
// wfq: B-frag layout for qkv GEMM; q rows pre-scaled by SCALE*LOG2E (attn uses exp2)
__global__ __launch_bounds__(256) void wtrans_kernel(
    const float* __restrict__ qk_w, const float* __restrict__ v_w,
    const float* __restrict__ proj_w, u16* __restrict__ wfq, u16* __restrict__ wfp) {
  int idx = blockIdx.x * 256 + threadIdx.x;          // 0..65535
  if (idx < 49152) {
    int j = idx & 7, l = (idx >> 3) & 63, kk = (idx >> 9) & 3, nt = idx >> 11;
    int k = kk * 32 + (l >> 4) * 8 + j;
    int oc = nt * 16 + (l & 15);
    float val;
    if (oc < 256) { val = qk_w[oc * 128 + k]; if (oc < 128) val *= SCALE * LOG2E; }
    else          { val = v_w[(oc - 256) * 128 + k]; }
    wfq[idx] = f2bf(val);
  } else {
    int r = idx - 49152;                             // 0..16383
    int j = r & 7, l = (r >> 3) & 63, kk = (r >> 9) & 3, mt = r >> 11;
    int oc = mt * 16 + (l & 15);
    int k = kk * 32 + (l >> 4) * 8 + j;
    wfp[r] = f2bf(proj_w[oc * 128 + k]);
  }
}

// ---------------- argmax over sims[pix][256] -> L[pix], first-index tie-break
__global__ __launch_bounds__(256) void argmax_kernel(
    const float* __restrict__ sims, int* __restrict__ L) {
  const int wave = threadIdx.x >> 6, lane = threadIdx.x & 63;
  const int pix = blockIdx.x * 4 + wave;
  const float4 s4 = *(const float4*)(sims + (size_t)pix * 256 + lane * 4);
  float bv = s4.x; int bi = lane * 4;
  if (s4.y > bv) { bv = s4.y; bi = lane * 4 + 1; }
  if (s4.z > bv) { bv = s4.z; bi = lane * 4 + 2; }
  if (s4.w > bv) { bv = s4.w; bi = lane * 4 + 3; }
  #pragma unroll
  for (int off = 32; off > 0; off >>= 1) {
    float ov = __shfl_down(bv, off);
    int   oi = __shfl_down(bi, off);
    if (ov > bv || (ov == bv && oi < bi)) { bv = ov; bi = oi; }
  }
  if (lane == 0) L[pix] = bi;
}

// ---------------- QKV GEMM (MFMA): x[b][c][hw] fp32 -> q/k/v bf16 [pix][128]
__global__ __launch_bounds__(256) void qkv_kernel(
    const float* __restrict__ x, const u16* __restrict__ wfq,
    u16* __restrict__ qb, u16* __restrict__ kb, u16* __restrict__ vb) {
  __shared__ __align__(16) u16 xs[64 * 136];         // [pix][c], pad 136 shorts
  const int t = threadIdx.x;
  const int pg0 = blockIdx.x * 64;
  const int b = blockIdx.x >> 8;
  const int hw0 = pg0 & (HWX - 1);
  const float* xb = x + (size_t)b * (CCH * HWX) + hw0;
  u32* xsw = (u32*)xs;
  #pragma unroll
  for (int it = 0; it < 16; ++it) {
    int flat = t + it * 256;                         // 0..4095 = 64 c2 x 64 pix
    int pix = flat & 63, c2 = flat >> 6;
    float f0 = xb[(size_t)(2 * c2) * HWX + pix];
    float f1 = xb[(size_t)(2 * c2 + 1) * HWX + pix];
    xsw[pix * 68 + c2] = pk2(f0, f1);
  }
  __syncthreads();

  const int w = t >> 6, lane = t & 63;
  const int l15 = lane & 15, quad = lane >> 4;

  s16x8 af[4][4];                                    // [mtile][kstep]
  #pragma unroll
  for (int m = 0; m < 4; ++m)
    #pragma unroll
    for (int kk = 0; kk < 4; ++kk)
      af[m][kk] = *(const s16x8*)(xs + (m * 16 + l15) * 136 + kk * 32 + quad * 8);

  f32x4 acc[6][4];                                   // [ntile][mtile]
  #pragma unroll
  for (int nt = 0; nt < 6; ++nt)
    #pragma unroll
    for (int m = 0; m < 4; ++m) acc[nt][m] = (f32x4){0.f, 0.f, 0.f, 0.f};

  const u16* wl = wfq + lane * 8;
  #pragma unroll
  for (int nt = 0; nt < 6; ++nt) {
    const int ntg = w * 6 + nt;
    s16x8 bf[4];
    #pragma unroll
    for (int kk = 0; kk < 4; ++kk)
      bf[kk] = *(const s16x8*)(wl + (size_t)(ntg * 4 + kk) * 512);
    #pragma unroll
    for (int m = 0; m < 4; ++m)
      #pragma unroll
      for (int kk = 0; kk < 4; ++kk)
        acc[nt][m] = __builtin_amdgcn_mfma_f32_16x16x32_bf16(af[m][kk], bf[kk], acc[nt][m], 0, 0, 0);
  }

  // epilogue: D row = pix = m*16 + quad*4 + r, col = oc = ntg*16 + l15
  #pragma unroll
  for (int nt = 0; nt < 6; ++nt) {
    const int oc = (w * 6 + nt) * 16 + l15;
    u16* base; int off;
    if (oc < 128)      { base = qb; off = oc; }
    else if (oc < 256) { base = kb; off = oc - 128; }
    else               { base = vb; off = oc - 256; }
    #pragma unroll
    for (int m = 0; m < 4; ++m) {
      const int pr = pg0 + m * 16 + quad * 4;
      #pragma unroll
      for (int r = 0; r < 4; ++r)
        base[((size_t)(pr + r) << 7) + off] = f2bf(acc[nt][m][r]);
    }
  }
}

// ---------------- attention (MFMA): block = 16x16 query tile x 1 head
// S^T = K.Q^T per 16-key tile (mask/exp/pack fused at mt granularity to keep
// <=4 f32x4 of S live -> no spill), P via wave-private LDS round-trip,
// out^T = V^T.P per 64-key chunk.
#define VROW 520   // vT row length (u16): 1040 B, 16B-aligned
#define PROW 72    // pT row length (u16): 144 B, 16B-aligned
__global__ __launch_bounds__(256, 2) void attn_kernel(
    const u16* __restrict__ qb, const u16* __restrict__ kb, const u16* __restrict__ vb,
    const int* __restrict__ L, u16* __restrict__ aob) {
  __shared__ __align__(16) u16 vT[32 * VROW];        // V^T [d][key] 33280 B
  __shared__ __align__(16) u16 pT[256 * PROW];       // P [q_local][key64] 36864 B
  __shared__ __align__(16) u32 meta[512];            // label | kc<<8 | rowmask16<<16
  const int t = threadIdx.x;
  const int bid = blockIdx.x;
  const int h = bid & 3, tj = (bid >> 2) & 7, ti = (bid >> 5) & 7, b = bid >> 8;
  const int i0 = ti * 16, j0 = tj * 16;
  const int r0 = i0 - 3, c0 = j0 - 3;                // neighborhood origin (may be <0)
  const size_t bbase = (size_t)b * HWX;

  // ---- stage V^T (transpose scatter): 512 keys x 4 dquads
  #pragma unroll
  for (int it = 0; it < 8; ++it) {
    int flat = t + it * 256;                         // 0..2047
    int key = flat >> 2, dq = flat & 3;
    int kr = key / 22, kc = key - kr * 22;
    int pr = min(max(r0 + kr, 0), HHH - 1), pc = min(max(c0 + kc, 0), WWW - 1);
    size_t g = ((bbase + (size_t)pr * WWW + pc) << 7) + h * HD + dq * 8;
    uint4 vv = *(const uint4*)(vb + g);
    u16* cb = vT + key + (size_t)(dq * 8) * VROW;
    cb[0 * VROW] = (u16)vv.x; cb[1 * VROW] = (u16)(vv.x >> 16);
    cb[2 * VROW] = (u16)vv.y; cb[3 * VROW] = (u16)(vv.y >> 16);
    cb[4 * VROW] = (u16)vv.z; cb[5 * VROW] = (u16)(vv.z >> 16);
    cb[6 * VROW] = (u16)vv.w; cb[7 * VROW] = (u16)(vv.w >> 16);
  }
  // ---- stage meta
  #pragma unroll
  for (int it = 0; it < 2; ++it) {
    int key = t + it * 256;
    int kr = key / 22, kc = key - kr * 22;
    int pr = min(max(r0 + kr, 0), HHH - 1), pc = min(max(c0 + kc, 0), WWW - 1);
    int lab = L[bbase + (size_t)pr * WWW + pc];
    u32 rm = 0;
    #pragma unroll
    for (int nt = 0; nt < 16; ++nt) {
      int rs = min(max(i0 + nt - 3, 0), HHH - 7) - r0;
      rm |= (u32)((u32)(kr - rs) <= 6u) << nt;
    }
    meta[key] = (u32)lab | ((u32)kc << 8) | (rm << 16);
  }
  __syncthreads();

  const int w = t >> 6, lane = t & 63;
  const int l15 = lane & 15, quad = lane >> 4;
  const int qj = j0 + l15;
  const u32 cs_rel = (u32)(min(max(qj - 3, 0), WWW - 7) - c0);
  const int ntg0 = w * 4;

  u32 slab[4];
  s16x8 qf[4];                                       // Q B-frags from global
  #pragma unroll
  for (int nt = 0; nt < 4; ++nt) {
    int qi = i0 + ntg0 + nt;
    slab[nt] = (u32)(((qi >> 3) << 4) | (qj >> 3));
    qf[nt] = *(const s16x8*)(qb + ((bbase + (size_t)qi * WWW + qj) << 7) + h * HD + quad * 8);
  }
  const int qrow0 = (ntg0 * 16 + l15) * PROW;        // wave-private pT rows

  f32x4 o[2][4];
  #pragma unroll
  for (int dmt = 0; dmt < 2; ++dmt)
    #pragma unroll
    for (int nt = 0; nt < 4; ++nt) o[dmt][nt] = (f32x4){0.f, 0.f, 0.f, 0.f};
  float sa[4] = {0.f, 0.f, 0.f, 0.f}, sm[4] = {0.f, 0.f, 0.f, 0.f};

  auto kaddr = [&](int key) -> const u16* {
    int kr = key / 22, kc = key - kr * 22;
    int pr = min(max(r0 + kr, 0), HHH - 1), pc = min(max(c0 + kc, 0), WWW - 1);
    return kb + ((bbase + (size_t)pr * WWW + pc) << 7) + h * HD + quad * 8;
  };

  // rolling K-frag pipeline: cur, nxt, prefetch 2 ahead
  s16x8 kf_cur = *(const s16x8*)kaddr(l15);
  s16x8 kf_nxt = *(const s16x8*)kaddr(16 + l15);

  for (int ch = 0; ch < 8; ++ch) {
    #pragma unroll
    for (int mt = 0; mt < 4; ++mt) {
      const s16x8 kf_pre = *(const s16x8*)kaddr(min(ch * 64 + mt * 16 + 32 + l15, 511));
      // S for this 16-key tile (4 f32x4 live)
      f32x4 s0 = __builtin_amdgcn_mfma_f32_16x16x32_bf16(kf_cur, qf[0], (f32x4){0.f,0.f,0.f,0.f}, 0, 0, 0);
      f32x4 s1 = __builtin_amdgcn_mfma_f32_16x16x32_bf16(kf_cur, qf[1], (f32x4){0.f,0.f,0.f,0.f}, 0, 0, 0);
      f32x4 s2 = __builtin_amdgcn_mfma_f32_16x16x32_bf16(kf_cur, qf[2], (f32x4){0.f,0.f,0.f,0.f}, 0, 0, 0);
      f32x4 s3 = __builtin_amdgcn_mfma_f32_16x16x32_bf16(kf_cur, qf[3], (f32x4){0.f,0.f,0.f,0.f}, 0, 0, 0);
      kf_cur = kf_nxt; kf_nxt = kf_pre;

      const uint4 me4 = *(const uint4*)(meta + ch * 64 + mt * 16 + quad * 4);
      u32 winc[4], lab[4], rm[4];
      { const u32 me[4] = {me4.x, me4.y, me4.z, me4.w};
        #pragma unroll
        for (int r = 0; r < 4; ++r) {
          winc[r] = (u32)(((me[r] >> 8) & 31u) - cs_rel <= 6u);
          lab[r]  = me[r] & 0xFFu;
          rm[r]   = me[r] >> (16 + ntg0);
        } }
      #pragma unroll
      for (int nt = 0; nt < 4; ++nt) {
        const f32x4 s_ = (nt == 0) ? s0 : (nt == 1) ? s1 : (nt == 2) ? s2 : s3;
        float pv[4];
        #pragma unroll
        for (int r = 0; r < 4; ++r) {
          const u32 win = winc[r] & ((rm[r] >> nt) & 1u);
          const u32 mem = win & (u32)(lab[r] == slab[nt]);
          const float e = __builtin_amdgcn_exp2f(s_[r]);
          sa[nt] += win ? e : 0.f;
          const float p = mem ? e : 0.f;
          sm[nt] += p;
          pv[r] = p;
        }
        *(uint2*)(pT + qrow0 + nt * 16 * PROW + mt * 16 + quad * 4) =
            make_uint2(pkru(pv[0], pv[1]), pkru(pv[2], pv[3]));
      }
    }
    // PV: out^T += V^T . P  (wave-private pT rows; in-wave DS ordering suffices)
    #pragma unroll
    for (int kk = 0; kk < 2; ++kk) {
      s16x8 pf[4];
      #pragma unroll
      for (int nt = 0; nt < 4; ++nt)
        pf[nt] = *(const s16x8*)(pT + qrow0 + nt * 16 * PROW + kk * 32 + quad * 8);
      #pragma unroll
      for (int dmt = 0; dmt < 2; ++dmt) {
        const s16x8 vf = *(const s16x8*)(vT + (size_t)(dmt * 16 + l15) * VROW + ch * 64 + kk * 32 + quad * 8);
        #pragma unroll
        for (int nt = 0; nt < 4; ++nt)
          o[dmt][nt] = __builtin_amdgcn_mfma_f32_16x16x32_bf16(vf, pf[nt], o[dmt][nt], 0, 0, 0);
      }
    }
  }

  // epilogue: reduce sa/sm across quads, scale, store out^T -> aob[pix][128]
  #pragma unroll
  for (int nt = 0; nt < 4; ++nt) {
    float a = sa[nt], m = sm[nt];
    a += __shfl_xor(a, 16); a += __shfl_xor(a, 32);
    m += __shfl_xor(m, 16); m += __shfl_xor(m, 32);
    const float inv = 1.f / (m + 1e-8f * a);
    const size_t pix = bbase + (size_t)(i0 + ntg0 + nt) * WWW + qj;
    u16* op = aob + (pix << 7) + h * HD + quad * 4;
    #pragma unroll
    for (int dmt = 0; dmt < 2; ++dmt) {
      f32x4 oo = o[dmt][nt];
      *(uint2*)(op + dmt * 16) = make_uint2(pk2(oo[0] * inv, oo[1] * inv),
                                            pk2(oo[2] * inv, oo[3] * inv));
    }
  }
}

// ---------------- proj GEMM (MFMA): ao bf16 [pix][128] @ wfp -> out fp32 [b][oc][hw]
__global__ __launch_bounds__(256) void proj_kernel(
    const u16* __restrict__ aob, const u16* __restrict__ wfp, float* __restrict__ out) {
  __shared__ __align__(16) u16 as_[64 * 136];
  const int t = threadIdx.x;
  const int pg0 = blockIdx.x * 64;
  const int b = blockIdx.x >> 8;
  const int hw0 = pg0 & (HWX - 1);
  #pragma unroll
  for (int it = 0; it < 4; ++it) {
    int flat = t + it * 256;                         // 0..1023 = 64 pix x 16 k8
    int pix = flat >> 4, k8 = flat & 15;
    uint4 v = *(const uint4*)(aob + ((size_t)(pg0 + pix) << 7) + k8 * 8);
    *(uint4*)(as_ + pix * 136 + k8 * 8) = v;
  }
  __syncthreads();

  const int w = t >> 6, lane = t & 63;
  const int l15 = lane & 15, quad = lane >> 4;

  s16x8 aw[2][4];                                    // [mt][kstep] from wfp
  const u16* wl = wfp + lane * 8;
  #pragma unroll
  for (int mt = 0; mt < 2; ++mt)
    #pragma unroll
    for (int kk = 0; kk < 4; ++kk)
      aw[mt][kk] = *(const s16x8*)(wl + (size_t)((2 * w + mt) * 4 + kk) * 512);

  f32x4 acc[2][4];                                   // [mt][nt]
  #pragma unroll
  for (int mt = 0; mt < 2; ++mt)
    #pragma unroll
    for (int nt = 0; nt < 4; ++nt) acc[mt][nt] = (f32x4){0.f, 0.f, 0.f, 0.f};

  #pragma unroll
  for (int nt = 0; nt < 4; ++nt) {
    s16x8 bf[4];
    #pragma unroll
    for (int kk = 0; kk < 4; ++kk)
      bf[kk] = *(const s16x8*)(as_ + (nt * 16 + l15) * 136 + kk * 32 + quad * 8);
    #pragma unroll
    for (int mt = 0; mt < 2; ++mt)
      #pragma unroll
      for (int kk = 0; kk < 4; ++kk)
        acc[mt][nt] = __builtin_amdgcn_mfma_f32_16x16x32_bf16(aw[mt][kk], bf[kk], acc[mt][nt], 0, 0, 0);
  }

  float* ob = out + (size_t)b * (CCH * HWX) + hw0;
  #pragma unroll
  for (int mt = 0; mt < 2; ++mt) {
    const int oc0 = (2 * w + mt) * 16 + quad * 4;
    #pragma unroll
    for (int nt = 0; nt < 4; ++nt) {
      const int pix = nt * 16 + l15;
      #pragma unroll
      for (int r = 0; r < 4; ++r)
        ob[(size_t)(oc0 + r) * HWX + pix] = acc[mt][nt][r];
    }
  }
}

extern "C" void kernel_launch(void* const* d_in, const int* in_sizes, int n_in,
                              void* d_out, int out_size, void* d_ws, size_t ws_size,
                              hipStream_t stream) {
  const float* x      = (const float*)d_in[0];
  const float* sims   = (const float*)d_in[1];
  const float* qk_w   = (const float*)d_in[2];
  const float* v_w    = (const float*)d_in[3];
  const float* proj_w = (const float*)d_in[4];
  float* out = (float*)d_out;

  // ws: q 32MiB | k 32MiB | v 32MiB | ao 32MiB (all bf16 [pix][128]) | L | wfq | wfp
  u16* qb  = (u16*)d_ws;
  u16* kb  = qb + 16777216;
  u16* vb  = kb + 16777216;
  u16* aob = vb + 16777216;
  int* L   = (int*)(aob + 16777216);
  u16* wfq = (u16*)(L + 131072);
  u16* wfp = wfq + 49152;

  wtrans_kernel<<<256, 256, 0, stream>>>(qk_w, v_w, proj_w, wfq, wfp);
  argmax_kernel<<<32768, 256, 0, stream>>>(sims, L);
  qkv_kernel<<<2048, 256, 0, stream>>>(x, wfq, qb, kb, vb);
  attn_kernel<<<2048, 256, 0, stream>>>(qb, kb, vb, L, aob);
  proj_kernel<<<2048, 256, 0, stream>>>(aob, wfp, out);
}

// Round 5
// 364.502 us; speedup vs baseline: 6.5371x; 1.1225x over previous
//
#include <hip/hip_runtime.h>
#include <hip/hip_bf16.h>

#define CCH 128
#define HHH 128
#define WWW 128
#define HWX 16384           // H*W
#define NHD 4
#define HD  32
#define SCALE 0.17677669529663687f
#define LOG2E 1.4426950408889634f

typedef unsigned int  u32;
typedef unsigned short u16;
typedef short s16x8 __attribute__((ext_vector_type(8)));   // 8 bf16 (4 VGPRs)
typedef float f32x4 __attribute__((ext_vector_type(4)));   // MFMA C/D frag

__device__ __forceinline__ u16 f2bf(float f) {
  u32 u = __float_as_uint(f);
  u += 0x7fffu + ((u >> 16) & 1u);
  return (u16)(u >> 16);
}
__device__ __forceinline__ u32 pk2(float a, float b) {
  return (u32)f2bf(a) | ((u32)f2bf(b) << 16);
}
// pack two fp32 -> 2 bf16 round-half-up (2 adds + 1 perm); inputs >= 0
__device__ __forceinline__ u32 pkru(float a, float b) {
  u32 ua = __float_as_uint(a) + 0x8000u;
  u32 ub = __float_as_uint(b) + 0x8000u;
  return __builtin_amdgcn_perm(ub, ua, 0x07060302);  // [ub.hi16 : ua.hi16]
}
// floor(k/22) for k in [0, 560): magic multiply
__device__ __forceinline__ int d22(int k) { return (k * 2980) >> 16; }

// ---------------- weight swizzle into MFMA fragment layouts (bf16)
// wfq: A/B-symmetric frag layout; q rows pre-scaled by SCALE*LOG2E (attn uses exp2)
__global__ __launch_bounds__(256) void wtrans_kernel(
    const float* __restrict__ qk_w, const float* __restrict__ v_w,
    const float* __restrict__ proj_w, u16* __restrict__ wfq, u16* __restrict__ wfp) {
  int idx = blockIdx.x * 256 + threadIdx.x;          // 0..65535
  if (idx < 49152) {
    int j = idx & 7, l = (idx >> 3) & 63, kk = (idx >> 9) & 3, nt = idx >> 11;
    int k = kk * 32 + (l >> 4) * 8 + j;
    int oc = nt * 16 + (l & 15);
    float val;
    if (oc < 256) { val = qk_w[oc * 128 + k]; if (oc < 128) val *= SCALE * LOG2E; }
    else          { val = v_w[(oc - 256) * 128 + k]; }
    wfq[idx] = f2bf(val);
  } else {
    int r = idx - 49152;                             // 0..16383
    int j = r & 7, l = (r >> 3) & 63, kk = (r >> 9) & 3, mt = r >> 11;
    int oc = mt * 16 + (l & 15);
    int k = kk * 32 + (l >> 4) * 8 + j;
    wfp[r] = f2bf(proj_w[oc * 128 + k]);
  }
}

// ---------------- argmax over sims[pix][256] -> L[pix], first-index tie-break
__global__ __launch_bounds__(256) void argmax_kernel(
    const float* __restrict__ sims, int* __restrict__ L) {
  const int wave = threadIdx.x >> 6, lane = threadIdx.x & 63;
  const int pix = blockIdx.x * 4 + wave;
  const float4 s4 = *(const float4*)(sims + (size_t)pix * 256 + lane * 4);
  float bv = s4.x; int bi = lane * 4;
  if (s4.y > bv) { bv = s4.y; bi = lane * 4 + 1; }
  if (s4.z > bv) { bv = s4.z; bi = lane * 4 + 2; }
  if (s4.w > bv) { bv = s4.w; bi = lane * 4 + 3; }
  #pragma unroll
  for (int off = 32; off > 0; off >>= 1) {
    float ov = __shfl_down(bv, off);
    int   oi = __shfl_down(bi, off);
    if (ov > bv || (ov == bv && oi < bi)) { bv = ov; bi = oi; }
  }
  if (lane == 0) L[pix] = bi;
}

// ---------------- QKV GEMM (MFMA): x[b][c][hw] fp32 -> q/k/v bf16 [pix][128]
// Transposed MFMA (D[m=oc][n=pix]) so lanes pack 4 consecutive oc -> LDS
// [pix][384] -> fully coalesced 16B global stores.
#define XTROW 392
__global__ __launch_bounds__(256) void qkv_kernel(
    const float* __restrict__ x, const u16* __restrict__ wfq,
    u16* __restrict__ qb, u16* __restrict__ kb, u16* __restrict__ vb) {
  __shared__ __align__(16) union { u16 xs[64 * 136]; u16 xt[64 * XTROW]; } sm;
  const int t = threadIdx.x;
  const int pg0 = blockIdx.x * 64;
  const int b = blockIdx.x >> 8;
  const int hw0 = pg0 & (HWX - 1);
  const float* xb = x + (size_t)b * (CCH * HWX) + hw0;
  u32* xsw = (u32*)sm.xs;
  #pragma unroll
  for (int it = 0; it < 16; ++it) {
    int flat = t + it * 256;                         // 0..4095 = 64 c2 x 64 pix
    int pix = flat & 63, c2 = flat >> 6;
    float f0 = xb[(size_t)(2 * c2) * HWX + pix];
    float f1 = xb[(size_t)(2 * c2 + 1) * HWX + pix];
    xsw[pix * 68 + c2] = pk2(f0, f1);
  }
  __syncthreads();

  const int wu = __builtin_amdgcn_readfirstlane(t >> 6);
  const int lane = t & 63;
  const int l15 = lane & 15, quad = lane >> 4;

  s16x8 af[4][4];                                    // [pix-tile][kstep]
  #pragma unroll
  for (int m = 0; m < 4; ++m)
    #pragma unroll
    for (int kk = 0; kk < 4; ++kk)
      af[m][kk] = *(const s16x8*)(sm.xs + (m * 16 + l15) * 136 + kk * 32 + quad * 8);
  __syncthreads();                                   // xs dead; xt reuses the space

  const u16* wl = wfq + lane * 8;
  #pragma unroll
  for (int nt = 0; nt < 6; ++nt) {
    const int ntg = wu * 6 + nt;
    s16x8 bf[4];
    #pragma unroll
    for (int kk = 0; kk < 4; ++kk)
      bf[kk] = *(const s16x8*)(wl + (size_t)(ntg * 4 + kk) * 512);
    #pragma unroll
    for (int m = 0; m < 4; ++m) {
      f32x4 acc = (f32x4){0.f, 0.f, 0.f, 0.f};
      #pragma unroll
      for (int kk = 0; kk < 4; ++kk)
        acc = __builtin_amdgcn_mfma_f32_16x16x32_bf16(bf[kk], af[m][kk], acc, 0, 0, 0);
      // lane: pix = m*16 + l15, oc = ntg*16 + quad*4 + (0..3)
      *(uint2*)(sm.xt + (m * 16 + l15) * XTROW + ntg * 16 + quad * 4) =
          make_uint2(pk2(acc[0], acc[1]), pk2(acc[2], acc[3]));
    }
  }
  __syncthreads();

  // coalesced write-out: q | k | v, 16B per lane
  u16* bufs[3] = {qb, kb, vb};
  #pragma unroll
  for (int bsel = 0; bsel < 3; ++bsel) {
    u16* dst = bufs[bsel];
    #pragma unroll
    for (int it = 0; it < 4; ++it) {
      int flat = t + it * 256;                       // 0..1023 = 64 pix x 16 g8
      int pix = flat >> 4, g8 = flat & 15;
      *(uint4*)(dst + ((size_t)(pg0 + pix) << 7) + g8 * 8) =
          *(const uint4*)(sm.xt + pix * XTROW + bsel * 128 + g8 * 8);
    }
  }
}

// ---------------- attention (MFMA): block = 16x16 query tile x 1 head
// Dense 512-key rectangle, but (key-tile x query-row) segments whose rows
// can't overlap the 7x7 window are skipped via wave-uniform scalar branches.
#define VROW 520   // vT row length (u16): 1040 B, 16B-aligned
#define PROW 72    // pT row length (u16): 144 B, 16B-aligned
__global__ __launch_bounds__(256, 2) void attn_kernel(
    const u16* __restrict__ qb, const u16* __restrict__ kb, const u16* __restrict__ vb,
    const int* __restrict__ L, u16* __restrict__ aob) {
  __shared__ __align__(16) u16 vT[32 * VROW];        // V^T [d][key] 33280 B
  __shared__ __align__(16) u16 pT[256 * PROW];       // P [q_local][key64] 36864 B
  __shared__ __align__(16) u32 meta[512];            // label | kc<<8 | rowmask16<<16
  __shared__ __align__(16) u32 koff[512];            // pr*W+pc per key
  const int t = threadIdx.x;
  const int bid = blockIdx.x;
  const int h = bid & 3, tj = (bid >> 2) & 7, ti = (bid >> 5) & 7, b = bid >> 8;
  const int i0 = ti * 16, j0 = tj * 16;
  const int r0 = i0 - 3, c0 = j0 - 3;                // neighborhood origin (may be <0)
  const size_t bbase = (size_t)b * HWX;

  // ---- stage V^T (transpose scatter): 512 keys x 4 dquads
  #pragma unroll
  for (int it = 0; it < 8; ++it) {
    int flat = t + it * 256;                         // 0..2047
    int key = flat >> 2, dq = flat & 3;
    int kr = d22(key), kc = key - kr * 22;
    int pr = min(max(r0 + kr, 0), HHH - 1), pc = min(max(c0 + kc, 0), WWW - 1);
    size_t g = ((bbase + (size_t)pr * WWW + pc) << 7) + h * HD + dq * 8;
    uint4 vv = *(const uint4*)(vb + g);
    u16* cb = vT + key + (size_t)(dq * 8) * VROW;
    cb[0 * VROW] = (u16)vv.x; cb[1 * VROW] = (u16)(vv.x >> 16);
    cb[2 * VROW] = (u16)vv.y; cb[3 * VROW] = (u16)(vv.y >> 16);
    cb[4 * VROW] = (u16)vv.z; cb[5 * VROW] = (u16)(vv.z >> 16);
    cb[6 * VROW] = (u16)vv.w; cb[7 * VROW] = (u16)(vv.w >> 16);
  }
  // ---- stage meta + key offset table
  #pragma unroll
  for (int it = 0; it < 2; ++it) {
    int key = t + it * 256;
    int kr = d22(key), kc = key - kr * 22;
    int pr = min(max(r0 + kr, 0), HHH - 1), pc = min(max(c0 + kc, 0), WWW - 1);
    koff[key] = (u32)(pr * WWW + pc);
    int lab = L[bbase + (size_t)pr * WWW + pc];
    u32 rm = 0;
    #pragma unroll
    for (int nt = 0; nt < 16; ++nt) {
      int rs = min(max(i0 + nt - 3, 0), HHH - 7) - r0;
      rm |= (u32)((u32)(kr - rs) <= 6u) << nt;
    }
    meta[key] = (u32)lab | ((u32)kc << 8) | (rm << 16);
  }
  __syncthreads();

  const int wu = __builtin_amdgcn_readfirstlane(t >> 6);   // wave-uniform SGPR
  const int lane = t & 63;
  const int l15 = lane & 15, quad = lane >> 4;
  const int qj = j0 + l15;
  const u32 cs_rel = (u32)(min(max(qj - 3, 0), WWW - 7) - c0);
  const int ntg0 = wu * 4;

  int rsr[4];                                        // window start row (key coords)
  u32 slab[4];
  s16x8 qf[4];                                       // Q frags from global
  #pragma unroll
  for (int nt = 0; nt < 4; ++nt) {
    int qi = i0 + ntg0 + nt;
    rsr[nt] = min(max(qi - 3, 0), HHH - 7) - r0;
    slab[nt] = (u32)(((qi >> 3) << 4) | (qj >> 3));
    qf[nt] = *(const s16x8*)(qb + ((bbase + (size_t)qi * WWW + qj) << 7) + h * HD + quad * 8);
  }
  const int qrow0 = (ntg0 * 16 + l15) * PROW;        // wave-private pT rows

  f32x4 o[2][4];
  #pragma unroll
  for (int dmt = 0; dmt < 2; ++dmt)
    #pragma unroll
    for (int nt = 0; nt < 4; ++nt) o[dmt][nt] = (f32x4){0.f, 0.f, 0.f, 0.f};
  float sa[4] = {0.f, 0.f, 0.f, 0.f}, sm[4] = {0.f, 0.f, 0.f, 0.f};

  auto kaddr = [&](int tile) -> const u16* {
    u32 vo = koff[tile + l15];
    return kb + ((bbase + vo) << 7) + h * HD + quad * 8;
  };

  // rolling K-frag pipeline: cur, nxt, prefetch 2 tiles ahead
  s16x8 kf_cur = *(const s16x8*)kaddr(0);
  s16x8 kf_nxt = *(const s16x8*)kaddr(16);

  for (int ch = 0; ch < 8; ++ch) {
    #pragma unroll
    for (int mt = 0; mt < 4; ++mt) {
      const int k0 = ch * 64 + mt * 16;
      const s16x8 kf_pre = *(const s16x8*)kaddr(min(k0 + 32, 496));
      const int rlo = d22(k0), rhi = d22(k0 + 15);
      if (rlo <= rsr[3] + 6 && rhi >= rsr[0]) {      // wave-uniform: tile near window
        const uint4 me4 = *(const uint4*)(meta + k0 + quad * 4);
        u32 winc[4], lab[4], rm[4];
        { const u32 me[4] = {me4.x, me4.y, me4.z, me4.w};
          #pragma unroll
          for (int r = 0; r < 4; ++r) {
            winc[r] = (u32)(((me[r] >> 8) & 31u) - cs_rel <= 6u);
            lab[r]  = me[r] & 0xFFu;
            rm[r]   = me[r] >> (16 + ntg0);
          } }
        #pragma unroll
        for (int nt = 0; nt < 4; ++nt) {
          if (rlo <= rsr[nt] + 6 && rhi >= rsr[nt]) {
            const f32x4 s_ = __builtin_amdgcn_mfma_f32_16x16x32_bf16(
                kf_cur, qf[nt], (f32x4){0.f, 0.f, 0.f, 0.f}, 0, 0, 0);
            float pv[4];
            #pragma unroll
            for (int r = 0; r < 4; ++r) {
              const u32 win = winc[r] & ((rm[r] >> nt) & 1u);
              const u32 mem = win & (u32)(lab[r] == slab[nt]);
              const float e = __builtin_amdgcn_exp2f(s_[r]);
              sa[nt] += win ? e : 0.f;
              const float p = mem ? e : 0.f;
              sm[nt] += p;
              pv[r] = p;
            }
            *(uint2*)(pT + qrow0 + nt * 16 * PROW + mt * 16 + quad * 4) =
                make_uint2(pkru(pv[0], pv[1]), pkru(pv[2], pv[3]));
          } else {
            *(uint2*)(pT + qrow0 + nt * 16 * PROW + mt * 16 + quad * 4) = make_uint2(0u, 0u);
          }
        }
      } else {                                       // whole tile out of window rows
        #pragma unroll
        for (int nt = 0; nt < 4; ++nt)
          *(uint2*)(pT + qrow0 + nt * 16 * PROW + mt * 16 + quad * 4) = make_uint2(0u, 0u);
      }
      kf_cur = kf_nxt; kf_nxt = kf_pre;
    }
    // PV: out^T += V^T . P  (wave-private pT rows; in-wave DS ordering suffices)
    #pragma unroll
    for (int kk = 0; kk < 2; ++kk) {
      const int kb0 = ch * 64 + kk * 32;
      const int r2lo = d22(kb0), r2hi = d22(kb0 + 31);
      if (r2lo <= rsr[3] + 6 && r2hi >= rsr[0]) {
        const s16x8 vf0 = *(const s16x8*)(vT + (size_t)l15 * VROW + kb0 + quad * 8);
        const s16x8 vf1 = *(const s16x8*)(vT + (size_t)(16 + l15) * VROW + kb0 + quad * 8);
        #pragma unroll
        for (int nt = 0; nt < 4; ++nt) {
          if (r2lo <= rsr[nt] + 6 && r2hi >= rsr[nt]) {
            const s16x8 pf = *(const s16x8*)(pT + qrow0 + nt * 16 * PROW + kk * 32 + quad * 8);
            o[0][nt] = __builtin_amdgcn_mfma_f32_16x16x32_bf16(vf0, pf, o[0][nt], 0, 0, 0);
            o[1][nt] = __builtin_amdgcn_mfma_f32_16x16x32_bf16(vf1, pf, o[1][nt], 0, 0, 0);
          }
        }
      }
    }
  }

  // epilogue: reduce sa/sm across quads, scale, store out^T -> aob[pix][128]
  #pragma unroll
  for (int nt = 0; nt < 4; ++nt) {
    float a = sa[nt], m = sm[nt];
    a += __shfl_xor(a, 16); a += __shfl_xor(a, 32);
    m += __shfl_xor(m, 16); m += __shfl_xor(m, 32);
    const float inv = 1.f / (m + 1e-8f * a);
    const size_t pix = bbase + (size_t)(i0 + ntg0 + nt) * WWW + qj;
    u16* op = aob + (pix << 7) + h * HD + quad * 4;
    #pragma unroll
    for (int dmt = 0; dmt < 2; ++dmt) {
      f32x4 oo = o[dmt][nt];
      *(uint2*)(op + dmt * 16) = make_uint2(pk2(oo[0] * inv, oo[1] * inv),
                                            pk2(oo[2] * inv, oo[3] * inv));
    }
  }
}

// ---------------- proj GEMM (MFMA): ao bf16 [pix][128] @ wfp -> out fp32 [b][oc][hw]
__global__ __launch_bounds__(256) void proj_kernel(
    const u16* __restrict__ aob, const u16* __restrict__ wfp, float* __restrict__ out) {
  __shared__ __align__(16) u16 as_[64 * 136];
  const int t = threadIdx.x;
  const int pg0 = blockIdx.x * 64;
  const int b = blockIdx.x >> 8;
  const int hw0 = pg0 & (HWX - 1);
  #pragma unroll
  for (int it = 0; it < 4; ++it) {
    int flat = t + it * 256;                         // 0..1023 = 64 pix x 16 k8
    int pix = flat >> 4, k8 = flat & 15;
    uint4 v = *(const uint4*)(aob + ((size_t)(pg0 + pix) << 7) + k8 * 8);
    *(uint4*)(as_ + pix * 136 + k8 * 8) = v;
  }
  __syncthreads();

  const int w = t >> 6, lane = t & 63;
  const int l15 = lane & 15, quad = lane >> 4;

  s16x8 aw[2][4];                                    // [mt][kstep] from wfp
  const u16* wl = wfp + lane * 8;
  #pragma unroll
  for (int mt = 0; mt < 2; ++mt)
    #pragma unroll
    for (int kk = 0; kk < 4; ++kk)
      aw[mt][kk] = *(const s16x8*)(wl + (size_t)((2 * w + mt) * 4 + kk) * 512);

  f32x4 acc[2][4];                                   // [mt][nt]
  #pragma unroll
  for (int mt = 0; mt < 2; ++mt)
    #pragma unroll
    for (int nt = 0; nt < 4; ++nt) acc[mt][nt] = (f32x4){0.f, 0.f, 0.f, 0.f};

  #pragma unroll
  for (int nt = 0; nt < 4; ++nt) {
    s16x8 bf[4];
    #pragma unroll
    for (int kk = 0; kk < 4; ++kk)
      bf[kk] = *(const s16x8*)(as_ + (nt * 16 + l15) * 136 + kk * 32 + quad * 8);
    #pragma unroll
    for (int mt = 0; mt < 2; ++mt)
      #pragma unroll
      for (int kk = 0; kk < 4; ++kk)
        acc[mt][nt] = __builtin_amdgcn_mfma_f32_16x16x32_bf16(aw[mt][kk], bf[kk], acc[mt][nt], 0, 0, 0);
  }

  float* ob = out + (size_t)b * (CCH * HWX) + hw0;
  #pragma unroll
  for (int mt = 0; mt < 2; ++mt) {
    const int oc0 = (2 * w + mt) * 16 + quad * 4;
    #pragma unroll
    for (int nt = 0; nt < 4; ++nt) {
      const int pix = nt * 16 + l15;
      #pragma unroll
      for (int r = 0; r < 4; ++r)
        ob[(size_t)(oc0 + r) * HWX + pix] = acc[mt][nt][r];
    }
  }
}

extern "C" void kernel_launch(void* const* d_in, const int* in_sizes, int n_in,
                              void* d_out, int out_size, void* d_ws, size_t ws_size,
                              hipStream_t stream) {
  const float* x      = (const float*)d_in[0];
  const float* sims   = (const float*)d_in[1];
  const float* qk_w   = (const float*)d_in[2];
  const float* v_w    = (const float*)d_in[3];
  const float* proj_w = (const float*)d_in[4];
  float* out = (float*)d_out;

  // ws: q 32MiB | k 32MiB | v 32MiB | ao 32MiB (all bf16 [pix][128]) | L | wfq | wfp
  u16* qb  = (u16*)d_ws;
  u16* kb  = qb + 16777216;
  u16* vb  = kb + 16777216;
  u16* aob = vb + 16777216;
  int* L   = (int*)(aob + 16777216);
  u16* wfq = (u16*)(L + 131072);
  u16* wfp = wfq + 49152;

  wtrans_kernel<<<256, 256, 0, stream>>>(qk_w, v_w, proj_w, wfq, wfp);
  argmax_kernel<<<32768, 256, 0, stream>>>(sims, L);
  qkv_kernel<<<2048, 256, 0, stream>>>(x, wfq, qb, kb, vb);
  attn_kernel<<<2048, 256, 0, stream>>>(qb, kb, vb, L, aob);
  proj_kernel<<<2048, 256, 0, stream>>>(aob, wfp, out);
}